// Round 3
// baseline (105.787 us; speedup 1.0000x reference)
//
#include <hip/hip_runtime.h>
#include <math.h>

// Problem constants: bs=32, en=256, dx=512, dz=256, heads=8, dh=32, L=1280.
//
// Mask is block-diagonal eyes: q<256 -> one-hot row; q=256+j -> exactly 4
// nonzeros {q, 512+j, 768+j, 1024+j} = col 256+j of centered state and col j
// of each centered obs. Wk folded into the query side:
//   score[b,j,h,m] = ( sum_e kb_m[e]*(wu[j,h,e]+wv[b,h,e]) + ubk+vbk ) / sqrt(32)
// with kb_m = raw_m - mean_m + pe, via raw/pe/ones dot rows.
//
// ws layout (floats):
//   pe   [32][256]             @ 0
//   u    [256][256]            @ 8192      (Q[256:]@Wq)
//   v    [32][256]             @ 73728     (pe@Wq + bq)
//   wu2  [8][256e][256j]       @ 81920
//   wv   [32][8][256e]         @ 606208
//   ubk  [256][8]              @ 671744
//   vbk  [32][8]               @ 673792
//   a    [32][256][4]          @ 674048    (head-averaged softmax weights)

// ---------------------------------------------------------------- k_uv
__global__ void k_uv(const float* __restrict__ Q, const float* __restrict__ Wq,
                     const float* __restrict__ bq, const float* __restrict__ bk,
                     float* __restrict__ pe, float* __restrict__ u,
                     float* __restrict__ v, float* __restrict__ ubk,
                     float* __restrict__ vbk) {
  __shared__ float row[256];
  const int f = threadIdx.x;
  const int blk = blockIdx.x;
  float rv;
  if (blk < 256) {
    rv = Q[(256 + blk) * 256 + f];
  } else {
    const int b = blk - 256;
    // sinusoidal PE over the BATCH axis (faithful quirk): pos=b, d_model=256
    const float dv = expf(-9.210340371976184f * (float)((f >> 1) << 1) * (1.0f / 256.0f));
    const float ang = (float)b * dv;
    rv = (f & 1) ? cosf(ang) : sinf(ang);
    pe[b * 256 + f] = rv;
  }
  row[f] = rv;
  __syncthreads();
  float acc = (blk < 256) ? 0.0f : bq[f];
  for (int e = 0; e < 256; ++e) acc += row[e] * Wq[e * 256 + f];
  if (blk < 256) u[blk * 256 + f] = acc;
  else           v[(blk - 256) * 256 + f] = acc;
  float val = acc * bk[f];
  val += __shfl_xor(val, 1);  val += __shfl_xor(val, 2);
  val += __shfl_xor(val, 4);  val += __shfl_xor(val, 8);
  val += __shfl_xor(val, 16);
  if ((f & 31) == 0) {
    const int h = f >> 5;
    if (blk < 256) ubk[blk * 8 + h] = val;
    else           vbk[(blk - 256) * 8 + h] = val;
  }
}

// ---------------------------------------------------------------- k_w
__global__ void k_w(const float* __restrict__ Wk, const float* __restrict__ u,
                    const float* __restrict__ v, float* __restrict__ wu2,
                    float* __restrict__ wv) {
  __shared__ float wrow[256];
  const int e = blockIdx.x;
  const int t = threadIdx.x;
  wrow[t] = Wk[e * 256 + t];
  __syncthreads();
  if (blockIdx.y == 0) {
    const float* ur = u + t * 256;
#pragma unroll
    for (int h = 0; h < 8; ++h) {
      float acc = 0.0f;
#pragma unroll
      for (int d = 0; d < 32; ++d) acc += ur[h * 32 + d] * wrow[h * 32 + d];
      wu2[(h * 256 + e) * 256 + t] = acc;
    }
  } else if (t < 32) {
    const float* vr = v + t * 256;
#pragma unroll
    for (int h = 0; h < 8; ++h) {
      float acc = 0.0f;
#pragma unroll
      for (int d = 0; d < 32; ++d) acc += vr[h * 32 + d] * wrow[h * 32 + d];
      wv[(t * 8 + h) * 256 + e] = acc;
    }
  }
}

// ---------------------------------------------------------------- k_score
// Block (bx: 64 j-tiles of 4, b: 32). 512 threads.
// Phase 1: cooperative stage of data columns and w = wu2+wv into LDS
//          (~10 independent float4 loads per thread -> one latency round).
// Phase 2: thread = (jl 0..3, hg 0..3 [2 heads each], egl 0..31 [8 e's]),
//          16 accumulators, all reads from LDS (padded rows: conflict-free).
// Reduce:  shfl_xor over lane bits 4,5 -> s_part across 8 waves -> 16
//          finalists do softmax for their 2 heads -> s_fin h-gather -> store.
__global__ __launch_bounds__(512, 4)
void k_score(const float* __restrict__ state, const float* __restrict__ o0,
             const float* __restrict__ o1, const float* __restrict__ o2,
             const float* __restrict__ pe, const float* __restrict__ wu2,
             const float* __restrict__ wv, const float* __restrict__ ubk,
             const float* __restrict__ vbk, float* __restrict__ a) {
  const int t = threadIdx.x;
  const int bx = blockIdx.x;       // 0..63
  const int b  = blockIdx.y;       // 0..31
  const int j0 = bx * 4;

  __shared__ float s_data[4 * 1280];          // [m][e*5 + jl], pad-5 rows
  __shared__ float s_w[8 * 1288];             // [h][e*5 + jl], padded h-plane
  __shared__ float s_pe[256];
  __shared__ float s_part[8][4][4][17];       // [wave][jl][hg][16+pad]
  __shared__ float s_fin[4][4][4];            // [jl][hg][m]

  // ---- stage data: cells c = m*256+e, 2 per thread
#pragma unroll
  for (int rep = 0; rep < 2; ++rep) {
    const int c = t + rep * 512;
    const int m = c >> 8;
    const int e = c & 255;
    const float* src;
    if (m == 0)      src = state + ((size_t)(b * 256 + e)) * 512 + 256 + j0;
    else if (m == 1) src = o0 + ((size_t)(b * 256 + e)) * 256 + j0;
    else if (m == 2) src = o1 + ((size_t)(b * 256 + e)) * 256 + j0;
    else             src = o2 + ((size_t)(b * 256 + e)) * 256 + j0;
    const float4 v4 = *(const float4*)src;
    float* dst = &s_data[m * 1280 + e * 5];
    dst[0] = v4.x; dst[1] = v4.y; dst[2] = v4.z; dst[3] = v4.w;
  }
  // ---- stage w = wu2 + wv: cells (h,e), 4 per thread
  {
    const int h = t >> 6;          // 0..7
    const int eb = t & 63;
#pragma unroll
    for (int rep = 0; rep < 4; ++rep) {
      const int e = eb + rep * 64;
      const float4 w4 = *(const float4*)(wu2 + ((size_t)(h * 256 + e)) * 256 + j0);
      const float wvc = wv[b * 2048 + h * 256 + e];
      float* dst = &s_w[h * 1288 + e * 5];
      dst[0] = w4.x + wvc; dst[1] = w4.y + wvc; dst[2] = w4.z + wvc; dst[3] = w4.w + wvc;
    }
  }
  if (t < 256) s_pe[t] = pe[b * 256 + t];
  __syncthreads();

  // ---- compute
  const int jl = t & 3;
  const int hg = (t >> 2) & 3;
  const int egl = t >> 4;          // 0..31
  const int h0 = hg * 2;

  float acc[16];                   // [h0:6][h1:6][sm:4]
#pragma unroll
  for (int k = 0; k < 16; ++k) acc[k] = 0.f;

  const float* dbase = s_data + jl;
  const float* wb0 = s_w + h0 * 1288 + jl;
  const float* wb1 = s_w + (h0 + 1) * 1288 + jl;

#pragma unroll
  for (int it = 0; it < 8; ++it) {
    const int e = egl * 8 + it;
    const int e5 = e * 5;
    const float s  = dbase[e5];
    const float x0 = dbase[1280 + e5];
    const float x1 = dbase[2560 + e5];
    const float x2 = dbase[3840 + e5];
    const float pv = s_pe[e];
    const float w0 = wb0[e5];
    const float w1 = wb1[e5];
    acc[0]  += s * w0;  acc[1]  += x0 * w0; acc[2]  += x1 * w0; acc[3]  += x2 * w0;
    acc[4]  += pv * w0; acc[5]  += w0;
    acc[6]  += s * w1;  acc[7]  += x0 * w1; acc[8]  += x1 * w1; acc[9]  += x2 * w1;
    acc[10] += pv * w1; acc[11] += w1;
    acc[12] += s; acc[13] += x0; acc[14] += x1; acc[15] += x2;
  }

  // reduce over egl-low (lane bits 4,5)
#pragma unroll
  for (int k = 0; k < 16; ++k) {
    acc[k] += __shfl_xor(acc[k], 16);
    acc[k] += __shfl_xor(acc[k], 32);
  }
  if ((t & 48) == 0) {
    const int w = t >> 6;
    float* p = &s_part[w][jl][hg][0];
#pragma unroll
    for (int k = 0; k < 16; ++k) p[k] = acc[k];
  }
  __syncthreads();

  if (t < 16) {
    const int fjl = t & 3;
    const int fhg = t >> 2;
    float tot[16];
#pragma unroll
    for (int k = 0; k < 16; ++k) tot[k] = 0.f;
#pragma unroll
    for (int w = 0; w < 8; ++w) {
      const float* p = &s_part[w][fjl][fhg][0];
#pragma unroll
      for (int k = 0; k < 16; ++k) tot[k] += p[k];
    }
    const int jj = j0 + fjl;
    const float m0 = tot[12] * (1.f / 256.f), m1 = tot[13] * (1.f / 256.f);
    const float m2 = tot[14] * (1.f / 256.f), m3 = tot[15] * (1.f / 256.f);
    const float inv = 0.17677669529663687f;  // 1/sqrt(32)
    float am0 = 0.f, am1 = 0.f, am2 = 0.f, am3 = 0.f;
#pragma unroll
    for (int k = 0; k < 2; ++k) {
      const int h = fhg * 2 + k;
      const float qb = ubk[jj * 8 + h] + vbk[b * 8 + h];
      const float c = tot[k * 6 + 4] + qb;
      const float s0 = (tot[k * 6 + 0] - m0 * tot[k * 6 + 5] + c) * inv;
      const float s1 = (tot[k * 6 + 1] - m1 * tot[k * 6 + 5] + c) * inv;
      const float s2 = (tot[k * 6 + 2] - m2 * tot[k * 6 + 5] + c) * inv;
      const float s3 = (tot[k * 6 + 3] - m3 * tot[k * 6 + 5] + c) * inv;
      const float mx = fmaxf(fmaxf(s0, s1), fmaxf(s2, s3));
      const float e0 = expf(s0 - mx), e1 = expf(s1 - mx);
      const float e2 = expf(s2 - mx), e3 = expf(s3 - mx);
      const float r = 1.f / (e0 + e1 + e2 + e3);
      am0 += e0 * r; am1 += e1 * r; am2 += e2 * r; am3 += e3 * r;
    }
    s_fin[fjl][fhg][0] = am0; s_fin[fjl][fhg][1] = am1;
    s_fin[fjl][fhg][2] = am2; s_fin[fjl][fhg][3] = am3;
  }
  __syncthreads();

  if (t < 4) {
    float am0 = 0.f, am1 = 0.f, am2 = 0.f, am3 = 0.f;
#pragma unroll
    for (int g = 0; g < 4; ++g) {
      am0 += s_fin[t][g][0]; am1 += s_fin[t][g][1];
      am2 += s_fin[t][g][2]; am3 += s_fin[t][g][3];
    }
    const int jj = j0 + t;
    float4 o = make_float4(am0 * 0.125f, am1 * 0.125f, am2 * 0.125f, am3 * 0.125f);
    *(float4*)(a + ((size_t)(b * 256 + jj) << 2)) = o;
  }
}

// ---------------------------------------------------------------- k_ns
__global__ void k_ns(const float* __restrict__ state, const float* __restrict__ o0,
                     const float* __restrict__ o1, const float* __restrict__ o2,
                     const float* __restrict__ a, float* __restrict__ out0) {
  const int t = threadIdx.x;   // 128
  const int e = blockIdx.x;    // 256
  const int b = blockIdx.y;    // 32
  const size_t rowS = ((size_t)b * 256 + e) * 512;
  const size_t rowO = ((size_t)b * 256 + e) * 256;
  if (t < 64) {
    const float4 vv = *(const float4*)(state + rowS + t * 4);
    *(float4*)(out0 + rowS + t * 4) = vv;
  } else {
    const int q0 = t * 4;
    const int j0 = q0 - 256;
    const float4 s  = *(const float4*)(state + rowS + q0);
    const float4 x0 = *(const float4*)(o0 + rowO + j0);
    const float4 x1 = *(const float4*)(o1 + rowO + j0);
    const float4 x2 = *(const float4*)(o2 + rowO + j0);
    const float rs[4] = {s.x, s.y, s.z, s.w};
    const float r0[4] = {x0.x, x0.y, x0.z, x0.w};
    const float r1[4] = {x1.x, x1.y, x1.z, x1.w};
    const float r2[4] = {x2.x, x2.y, x2.z, x2.w};
    float ro[4];
#pragma unroll
    for (int k = 0; k < 4; ++k) {
      const float4 aa = *(const float4*)(a + (((size_t)b * 256) + (j0 + k)) * 4);
      ro[k] = aa.x * rs[k] + aa.y * r0[k] + aa.z * r1[k] + aa.w * r2[k];
    }
    const float4 o = make_float4(ro[0], ro[1], ro[2], ro[3]);
    *(float4*)(out0 + rowS + q0) = o;
  }
}

// ---------------------------------------------------------------- k_at
__global__ void k_at(const float* __restrict__ a, float* __restrict__ out1) {
  const int t = threadIdx.x;   // 320 (1280/4)
  const int q = blockIdx.x;    // 512
  const int b = blockIdx.y;    // 32
  const int l0 = t * 4;
  float v0 = 0.f, v1 = 0.f, v2 = 0.f, v3 = 0.f;
  if (q < 256) {
    if (q == l0) v0 = 1.f; else if (q == l0 + 1) v1 = 1.f;
    else if (q == l0 + 2) v2 = 1.f; else if (q == l0 + 3) v3 = 1.f;
  } else {
    const int j = q - 256;
    const int s = j & 3;
    const float* ap = a + (((size_t)b * 256) + j) * 4;
    float av = 0.f; bool hit = false;
    if (l0 == (q & ~3))              { av = ap[0]; hit = true; }
    else if (l0 == ((512 + j) & ~3)) { av = ap[1]; hit = true; }
    else if (l0 == ((768 + j) & ~3)) { av = ap[2]; hit = true; }
    else if (l0 == ((1024 + j) & ~3)){ av = ap[3]; hit = true; }
    if (hit) { if (s == 0) v0 = av; else if (s == 1) v1 = av; else if (s == 2) v2 = av; else v3 = av; }
  }
  const float4 o = make_float4(v0, v1, v2, v3);
  *(float4*)(out1 + ((size_t)b * 512 + q) * 1280 + l0) = o;
}

extern "C" void kernel_launch(void* const* d_in, const int* in_sizes, int n_in,
                              void* d_out, int out_size, void* d_ws, size_t ws_size,
                              hipStream_t stream) {
  const float* state = (const float*)d_in[0];
  const float* obs0  = (const float*)d_in[1];
  const float* obs1  = (const float*)d_in[2];
  const float* obs2  = (const float*)d_in[3];
  const float* Q     = (const float*)d_in[4];
  const float* Wq    = (const float*)d_in[5];
  const float* bq    = (const float*)d_in[6];
  const float* Wk    = (const float*)d_in[7];
  const float* bk    = (const float*)d_in[8];

  float* out0 = (float*)d_out;                       // new_state [32,256,512]
  float* out1 = out0 + (size_t)32 * 256 * 512;       // atten [32,512,1280]

  float* ws  = (float*)d_ws;
  float* pe  = ws;              // 8192
  float* u   = pe + 8192;       // 65536
  float* v   = u + 65536;       // 8192
  float* wu2 = v + 8192;        // 524288
  float* wv  = wu2 + 524288;    // 65536
  float* ubk = wv + 65536;      // 2048
  float* vbk = ubk + 2048;      // 256
  float* a   = vbk + 256;       // 32768

  k_uv<<<288, 256, 0, stream>>>(Q, Wq, bq, bk, pe, u, v, ubk, vbk);
  k_w<<<dim3(256, 2), 256, 0, stream>>>(Wk, u, v, wu2, wv);
  k_score<<<dim3(64, 32), 512, 0, stream>>>(state, obs0, obs1, obs2, pe, wu2, wv, ubk, vbk, a);
  k_ns<<<dim3(256, 32), 128, 0, stream>>>(state, obs0, obs1, obs2, a, out0);
  k_at<<<dim3(512, 32), 320, 0, stream>>>(a, out1);
}